// Round 16
// baseline (92.019 us; speedup 1.0000x reference)
//
#include <hip/hip_runtime.h>
#include <cstdint>
#include <cstddef>

#define B_ 4
#define S_ 1024
#define D_ 256
#define H_ 8

typedef unsigned short u16;
typedef __attribute__((ext_vector_type(8))) short short8v;     // 8 x bf16 MFMA operand
typedef __attribute__((ext_vector_type(8))) _Float16 half8v;   // 8 x fp16 MFMA operand
typedef __attribute__((ext_vector_type(4))) float f32x4;       // MFMA accumulator
typedef __attribute__((ext_vector_type(4))) u16 u16x4;
typedef __attribute__((ext_vector_type(8))) u16 u16x8;

__device__ inline u16 f2b(float f) {            // fp32 -> bf16 RN-even
  unsigned u = __builtin_bit_cast(unsigned, f);
  unsigned r = (u + 0x7FFFu + ((u >> 16) & 1u)) >> 16;
  return (u16)r;
}
__device__ inline float b2f(u16 h) {
  return __builtin_bit_cast(float, ((unsigned)h) << 16);
}
__device__ inline u16 f2h(float f) {
  return __builtin_bit_cast(u16, (_Float16)f);
}
__device__ inline f32x4 mfma16(short8v a, short8v b, f32x4 c) {
  return __builtin_amdgcn_mfma_f32_16x16x32_bf16(a, b, c, 0, 0, 0);
}
__device__ inline f32x4 mfma16h(half8v a, half8v b, f32x4 c) {
  return __builtin_amdgcn_mfma_f32_16x16x32_f16(a, b, c, 0, 0, 0);
}
__device__ __forceinline__ void gl16(const u16* g, u16* l) {
  __builtin_amdgcn_global_load_lds((const uint32_t*)g, (uint32_t*)l, 16, 0, 0);
}

// ---- fused LayerNorm (0..1023) + W transpose (1024..1535) + k2 zero (1536..1551) ----
__global__ __launch_bounds__(256) void lnwt_kernel(
    const float* __restrict__ x, const float* __restrict__ w,
    const float* __restrict__ Wq, const float* __restrict__ Wk,
    const float* __restrict__ Wv, const float* __restrict__ Wo,
    u16* __restrict__ xf, u16* __restrict__ WTf, u16* __restrict__ WoTf,
    float* __restrict__ k2) {
  const int bid = blockIdx.x;
  const int tid = threadIdx.x;
  if (bid < 1024) {
    // ---- LayerNorm: wave-per-row, 4 rows per block ----
    const int wid = tid >> 6, lane = tid & 63;
    const int row = bid * 4 + wid;                      // 0..4095
    const float4 v4 = *reinterpret_cast<const float4*>(x + (size_t)row * D_ + lane * 4);
    const float4 w4 = *reinterpret_cast<const float4*>(w + lane * 4);
    float s  = v4.x + v4.y + v4.z + v4.w;
    float s2 = v4.x * v4.x + v4.y * v4.y + v4.z * v4.z + v4.w * v4.w;
#pragma unroll
    for (int off = 1; off < 64; off <<= 1) {
      s  += __shfl_xor(s, off);
      s2 += __shfl_xor(s2, off);
    }
    const float mu  = s * (1.0f / D_);
    const float var = s2 * (1.0f / D_) - mu * mu;
    const float rr  = rsqrtf(var + 1e-5f);
    u16x4 o;
    o[0] = f2h((v4.x - mu) * rr * w4.x);
    o[1] = f2h((v4.y - mu) * rr * w4.y);
    o[2] = f2h((v4.z - mu) * rr * w4.z);
    o[3] = f2h((v4.w - mu) * rr * w4.w);
    *reinterpret_cast<u16x4*>(xf + (size_t)row * D_ + lane * 4) = o;
  } else if (bid >= 1536) {
    // ---- zero k2: 16 blocks x 256 thr x 32B = 128KB ----
    const size_t i = ((size_t)(bid - 1536) * 256 + tid) * 8;
    const float4 z4 = {0.f, 0.f, 0.f, 0.f};
    *reinterpret_cast<float4*>(k2 + i)     = z4;
    *reinterpret_cast<float4*>(k2 + i + 4) = z4;
  } else {
    // ---- weight transpose: 4 tiles per block ----
    __shared__ float t[32][33];
    const int tc = tid & 31, tr = tid >> 5;
    const int zb = (bid - 1024) * 4;
#pragma unroll
    for (int i = 0; i < 4; ++i) {
      const int z = zb + i;                             // 0..2047
      if (i) __syncthreads();                           // prior tile's reads done
      if (z < 1536) {
        const int wm = z >> 6;                          // 0..23
        const int mat = wm >> 3, h = wm & 7;
        const float* src = (mat == 0 ? Wq : mat == 1 ? Wk : Wv) + (size_t)h * 65536;
        const int t6 = z & 63;
        const int r0 = (t6 >> 3) * 32, c0 = (t6 & 7) * 32;
#pragma unroll
        for (int k = 0; k < 4; ++k)
          t[tr + k * 8][tc] = src[(size_t)(r0 + tr + k * 8) * 256 + c0 + tc];
        __syncthreads();
        u16* df = WTf + (size_t)wm * 65536;
#pragma unroll
        for (int k = 0; k < 4; ++k) {
          const float v = t[tc][tr + k * 8];
          df[(size_t)(c0 + tr + k * 8) * 256 + r0 + tc] = f2h(v);
        }
      } else {
        const int z2 = z - 1536;                        // 0..511
        const int r0 = (z2 >> 3) * 32, c0 = (z2 & 7) * 32;
#pragma unroll
        for (int k = 0; k < 4; ++k)
          t[tr + k * 8][tc] = Wo[(size_t)(r0 + tr + k * 8) * 256 + c0 + tc];
        __syncthreads();
#pragma unroll
        for (int k = 0; k < 4; ++k) {
          const float v = t[tc][tr + k * 8];
          WoTf[(size_t)(c0 + tr + k * 8) * 2048 + r0 + tc] = f2b(v);
        }
      }
    }
  }
}

// ---------------- Q/K/V projection: single-term fp16, BK=64; K-epilogue emits k2 ----------------
__global__ __launch_bounds__(256, 3) void proj_kernel(
    const u16* __restrict__ xf, const u16* __restrict__ WTf,
    u16* __restrict__ Qf, u16* __restrict__ Kf,
    u16* __restrict__ Vt, float* __restrict__ k2g) {
  const int z = blockIdx.y;            // 0..23
  const int mat = z >> 3, h = z & 7;
  const int xb = blockIdx.x;           // 0..63

  const u16 *Ap, *Bp;
  int arow0, brow0;
  if (mat < 2) {            // A = WT (M = e), B = x (N = s)
    Ap = WTf + (size_t)z * 65536; arow0 = (xb >> 5) * 128;
    Bp = xf;                      brow0 = (xb & 31) * 128;
  } else {                  // A = x (M = s), B = WT (N = d)
    Ap = xf;                      arow0 = (xb & 31) * 128;
    Bp = WTf + (size_t)z * 65536; brow0 = (xb >> 5) * 128;
  }

  __shared__ u16 LS[2 * 128 * 64];     // 32KB: A tile | B tile (reused by epilogue)
  u16* AS = LS; u16* BS = LS + 128 * 64;
  char* LSb = (char*)LS;
  char* ASb = (char*)AS; char* BSb = (char*)BS;

  const int tid = threadIdx.x;
  const int w = tid >> 6, lane = tid & 63;
  const int lr = lane & 15, lh = lane >> 4;
  const int wm = w >> 1, wn = w & 1;

  f32x4 acc[4][4];
#pragma unroll
  for (int i = 0; i < 4; ++i)
#pragma unroll
    for (int j = 0; j < 4; ++j) acc[i][j] = (f32x4){0.f, 0.f, 0.f, 0.f};

  for (int k0 = 0; k0 < 256; k0 += 64) {
    __syncthreads();
#pragma unroll
    for (int j = 0; j < 4; ++j) {
      const int c0 = j * 256 + w * 64;
      const int c = c0 + lane;
      const int m = c >> 3, sl = c & 7;
      const int l = sl ^ (m & 7);
      gl16(Ap + (size_t)(arow0 + m) * 256 + k0 + l * 8, AS + c0 * 8);
    }
#pragma unroll
    for (int j = 0; j < 4; ++j) {
      const int c0 = j * 256 + w * 64;
      const int c = c0 + lane;
      const int n = c >> 3, sl = c & 7;
      const int l = sl ^ (n & 7);
      gl16(Bp + (size_t)(brow0 + n) * 256 + k0 + l * 8, BS + c0 * 8);
    }
    __syncthreads();

#pragma unroll
    for (int ks = 0; ks < 2; ++ks) {
      half8v af[4], bf[4];
#pragma unroll
      for (int mf = 0; mf < 4; ++mf) {
        const int m = wm * 64 + mf * 16 + lr;
        af[mf] = *reinterpret_cast<const half8v*>(
            ASb + m * 128 + (((ks * 4 + lh) * 16) ^ ((m & 7) << 4)));
      }
#pragma unroll
      for (int nf = 0; nf < 4; ++nf) {
        const int n = wn * 64 + nf * 16 + lr;
        bf[nf] = *reinterpret_cast<const half8v*>(
            BSb + n * 128 + (((ks * 4 + lh) * 16) ^ ((n & 7) << 4)));
      }
      __builtin_amdgcn_s_setprio(1);
#pragma unroll
      for (int mf = 0; mf < 4; ++mf)
#pragma unroll
        for (int nf = 0; nf < 4; ++nf)
          acc[mf][nf] = mfma16h(af[mf], bf[nf], acc[mf][nf]);
      __builtin_amdgcn_s_setprio(0);
    }
  }

  __syncthreads();

  if (mat < 2) {
    u16* Hf = (mat == 0) ? Qf : Kf;
#pragma unroll
    for (int mf = 0; mf < 4; ++mf)
#pragma unroll
      for (int nf = 0; nf < 4; ++nf) {
        const int sl_ = wn * 64 + nf * 16 + lr;
        const int el_ = wm * 64 + mf * 16 + lh * 4;
        u16x4 hv;
#pragma unroll
        for (int r = 0; r < 4; ++r) hv[r] = f2h(acc[mf][nf][r]);
        *reinterpret_cast<u16x4*>(LSb + sl_ * 256 + ((el_ * 2) ^ ((sl_ & 7) << 4))) = hv;
      }
    // ---- k2 partials (K only): per s-row, sum of rounded-fp16 squares ----
    if (mat == 1) {
#pragma unroll
      for (int nf = 0; nf < 4; ++nf) {
        float p = 0.f;
#pragma unroll
        for (int mf = 0; mf < 4; ++mf)
#pragma unroll
          for (int r = 0; r < 4; ++r) {
            const float v = (float)(_Float16)acc[mf][nf][r];
            p = fmaf(v, v, p);
          }
        p += __shfl_xor(p, 16);
        p += __shfl_xor(p, 32);
        if (lh == 0) {
          const int s = brow0 + wn * 64 + nf * 16 + lr;
          const int bb = s >> 10;
          atomicAdd(&k2g[(size_t)(bb * H_ + h) * S_ + (s & 1023)], p);
        }
      }
    }
    __syncthreads();
#pragma unroll
    for (int i = 0; i < 8; ++i) {
      const int c = i * 256 + tid;
      const int sl_ = c >> 4, ch = c & 15;
      const u16x8 v = *reinterpret_cast<const u16x8*>(
          LSb + sl_ * 256 + ((ch * 16) ^ ((sl_ & 7) << 4)));
      const int s = brow0 + sl_;
      const int bb = s >> 10;
      *reinterpret_cast<u16x8*>(
          Hf + ((size_t)(bb * H_ + h) * S_ + (s & 1023)) * D_ + arow0 + ch * 8) = v;
    }
  } else {
#pragma unroll
    for (int mf = 0; mf < 4; ++mf)
#pragma unroll
      for (int nf = 0; nf < 4; ++nf) {
        const int dl_ = wn * 64 + nf * 16 + lr;
        const int sl_ = wm * 64 + mf * 16 + lh * 4;
        u16x4 hv;
#pragma unroll
        for (int r = 0; r < 4; ++r) hv[r] = f2b(acc[mf][nf][r]);
        *reinterpret_cast<u16x4*>(LSb + dl_ * 256 + ((sl_ * 2) ^ ((dl_ & 7) << 4))) = hv;
      }
    __syncthreads();
#pragma unroll
    for (int i = 0; i < 8; ++i) {
      const int c = i * 256 + tid;
      const int dl_ = c >> 4, ch = c & 15;
      const u16x8 v = *reinterpret_cast<const u16x8*>(
          LSb + dl_ * 256 + ((ch * 16) ^ ((dl_ & 7) << 4)));
      const int d = brow0 + dl_;
      const int sg = arow0 + ch * 8;
      const int bb = sg >> 10;
      *reinterpret_cast<u16x8*>(
          Vt + ((size_t)(bb * H_ + h) * D_ + d) * S_ + (sg & 1023)) = v;
    }
  }
}

// ---------------- fused RBF attention v17: 2-barrier counted-vmcnt pipeline + tail peel ------
__global__ __launch_bounds__(256, 2) void attn_kernel(
    const u16* __restrict__ Qf, const u16* __restrict__ Kf,
    const u16* __restrict__ Vt, const float* __restrict__ k2,
    u16* __restrict__ aOf) {
  const int bh  = blockIdx.x;   // 0..31 (fast -> XCD locality)
  const int qt  = blockIdx.y;   // 0..15
  const int tid = threadIdx.x;
  const int w = tid >> 6, lane = tid & 63;
  const int lr = lane & 15, lh = lane >> 4;
  const int qg = w >> 1, kvh = w & 1;

  __shared__ u16 KS[64 * 256];    // fp16, rows 512B swizzled     (32KB)
  __shared__ u16 VS[256 * 64];    // bf16, rows 128B swizzled     (32KB)
  __shared__ u16 PS[64 * 64];     // bf16, rows 128B swizzled     (8KB)
  __shared__ float K2S[1024];     // k2 row for this bh           (4KB)
  char* KB = (char*)KS; char* VB = (char*)VS; char* PB = (char*)PS;

  half8v qf[2][8];
#pragma unroll
  for (int at = 0; at < 2; ++at) {
    const int qrow = qt * 64 + qg * 32 + at * 16 + lr;
    const size_t qbase = ((size_t)(bh * S_) + qrow) * D_ + lh * 8;
#pragma unroll
    for (int ds = 0; ds < 8; ++ds)
      qf[at][ds] = *reinterpret_cast<const half8v*>(Qf + qbase + ds * 32);
  }

  const size_t kgbase = (size_t)(bh * S_);
  const size_t vgbase = (size_t)(bh * D_);

  // ---- prologue: issue K[0] (8), k2 (1), V[0] (8); q2 computes under the flight ----
#pragma unroll
  for (int j = 0; j < 8; ++j) {
    const int c0 = j * 256 + w * 64;
    const int c = c0 + lane;
    const int row = c >> 5, slot = c & 31;
    gl16(Kf + (kgbase + row) * D_ + ((slot ^ (row & 7)) << 3), KS + c0 * 8);
  }
  gl16((const u16*)(k2 + (size_t)bh * S_) + tid * 8, (u16*)K2S + tid * 8);
#pragma unroll
  for (int j = 0; j < 8; ++j) {
    const int c0 = j * 256 + w * 64;
    const int c = c0 + lane;
    const int d = c >> 3, slot = c & 7;
    gl16(Vt + (vgbase + d) * S_ + ((slot ^ (d & 7)) << 3), VS + c0 * 8);
  }

  // ---- q2 fully in-register: after xor16+xor32 every lane holds q2(row=lr) ----
  float q2v[2];
#pragma unroll
  for (int at = 0; at < 2; ++at) {
    float p = 0.f;
#pragma unroll
    for (int ds = 0; ds < 8; ++ds)
#pragma unroll
      for (int j = 0; j < 8; ++j) {
        const float v = (float)qf[at][ds][j];
        p = fmaf(v, v, p);
      }
    p += __shfl_xor(p, 16);
    p += __shfl_xor(p, 32);
    q2v[at] = p;
  }

  asm volatile("s_waitcnt vmcnt(8)" ::: "memory");   // K[0]+k2 landed; V[0] in flight
  __builtin_amdgcn_sched_barrier(0);
  __builtin_amdgcn_s_barrier();

  f32x4 oacc[4][4];
#pragma unroll
  for (int i = 0; i < 4; ++i)
#pragma unroll
    for (int j = 0; j < 4; ++j) oacc[i][j] = (f32x4){0.f, 0.f, 0.f, 0.f};

  for (int kt = 0; kt < 16; ++kt) {
    const int last = (kt == 15);

    // per-wave counted wait: K[kt] landed (8 newest outstanding = V[kt], still flying)
    asm volatile("s_waitcnt vmcnt(8)" ::: "memory");
    __builtin_amdgcn_sched_barrier(0);

    // k2 slice for this tile from LDS (broadcast reads, conflict-free)
    f32x4 k2v[2];
#pragma unroll
    for (int bt = 0; bt < 2; ++bt)
      k2v[bt] = *reinterpret_cast<const f32x4*>(
          K2S + kt * 64 + kvh * 32 + bt * 16 + lh * 4);

    // ---- QK^T swapped: pacc = mfma(K, Q) -> lane holds P^T: rows kv=lh*4+r, col q=lr ----
    f32x4 pacc[2][2];
#pragma unroll
    for (int at = 0; at < 2; ++at)
#pragma unroll
      for (int bt = 0; bt < 2; ++bt) pacc[at][bt] = (f32x4){0.f, 0.f, 0.f, 0.f};
#pragma unroll
    for (int ds = 0; ds < 8; ++ds) {
      half8v kf[2];
#pragma unroll
      for (int bt = 0; bt < 2; ++bt) {
        const int krow = kvh * 32 + bt * 16 + lr;
        kf[bt] = *reinterpret_cast<const half8v*>(
            KB + krow * 512 + (((ds * 64) + lh * 16) ^ ((krow & 7) << 4)));
      }
      __builtin_amdgcn_s_setprio(1);
#pragma unroll
      for (int at = 0; at < 2; ++at)
#pragma unroll
        for (int bt = 0; bt < 2; ++bt)
          pacc[at][bt] = mfma16h(kf[bt], qf[at][ds], pacc[at][bt]);
      __builtin_amdgcn_s_setprio(0);
    }

    // ---- exp + P^T write: u16x4 along kv per (at,bt) -> 4 x ds_write_b64 ----
#pragma unroll
    for (int at = 0; at < 2; ++at) {
      const int q = qg * 32 + at * 16 + lr;
#pragma unroll
      for (int bt = 0; bt < 2; ++bt) {
        const int kv0 = kvh * 32 + bt * 16 + lh * 4;
        u16x4 pv;
#pragma unroll
        for (int r = 0; r < 4; ++r) {
          float d2 = q2v[at] + k2v[bt][r] - 2.0f * pacc[at][bt][r];
          d2 = fmaxf(d2, 0.f);
          pv[r] = f2b(__expf(-d2));
        }
        *reinterpret_cast<u16x4*>(PB + q * 128 + ((kv0 * 2) ^ ((q & 7) << 4))) = pv;
      }
    }
    asm volatile("s_waitcnt vmcnt(0) lgkmcnt(0)" ::: "memory");  // V[kt] landed; KS reads + P done
    __builtin_amdgcn_sched_barrier(0);
    __builtin_amdgcn_s_barrier();          // BAR A

    // ---- issue K[kt+1] staging (skipped on last iter): waited per-wave at next loop top ----
    if (!last) {
#pragma unroll
      for (int j = 0; j < 8; ++j) {
        const int c0 = j * 256 + w * 64;
        const int c = c0 + lane;
        const int row = c >> 5, slot = c & 31;
        gl16(Kf + (kgbase + (kt + 1) * 64 + row) * D_ + ((slot ^ (row & 7)) << 3),
             KS + c0 * 8);
      }
    }

    // ---- PV: wave owns d in [w*64, w*64+64) for all 64 q ----
    short8v vfr[4][2];
#pragma unroll
    for (int dt = 0; dt < 4; ++dt)
#pragma unroll
      for (int ks = 0; ks < 2; ++ks) {
        const int d = w * 64 + dt * 16 + lr;
        vfr[dt][ks] = *reinterpret_cast<const short8v*>(
            VB + d * 128 + (((ks * 64) + lh * 16) ^ ((d & 7) << 4)));
      }
#pragma unroll
    for (int pq = 0; pq < 4; ++pq) {
      short8v pa[2];
#pragma unroll
      for (int ks = 0; ks < 2; ++ks) {
        const int q = pq * 16 + lr;
        pa[ks] = *reinterpret_cast<const short8v*>(
            PB + q * 128 + (((ks * 64) + lh * 16) ^ ((q & 7) << 4)));
      }
      __builtin_amdgcn_s_setprio(1);
#pragma unroll
      for (int dt = 0; dt < 4; ++dt) {
        oacc[pq][dt] = mfma16(pa[0], vfr[dt][0], oacc[pq][dt]);
        oacc[pq][dt] = mfma16(pa[1], vfr[dt][1], oacc[pq][dt]);
      }
      __builtin_amdgcn_s_setprio(0);
    }
    if (!last) {
      asm volatile("s_waitcnt lgkmcnt(0)" ::: "memory");   // VS/PS reads done (no vmem wait)
      __builtin_amdgcn_sched_barrier(0);
      __builtin_amdgcn_s_barrier();        // BAR B

      // ---- issue V[kt+1] staging: flies under next QK, drained at next BAR A ----
#pragma unroll
      for (int j = 0; j < 8; ++j) {
        const int c0 = j * 256 + w * 64;
        const int c = c0 + lane;
        const int d = c >> 3, slot = c & 7;
        gl16(Vt + (vgbase + d) * S_ + (kt + 1) * 64 + ((slot ^ (d & 7)) << 3),
             VS + c0 * 8);
      }
    }
  }

  const int bb = bh >> 3, hh = bh & 7;
#pragma unroll
  for (int pq = 0; pq < 4; ++pq)
#pragma unroll
    for (int dt = 0; dt < 4; ++dt)
#pragma unroll
      for (int r = 0; r < 4; ++r) {
        const int s = qt * 64 + pq * 16 + lh * 4 + r;
        const int d = w * 64 + dt * 16 + lr;
        const size_t idx = ((size_t)(bb * S_) + s) * (H_ * D_) + hh * D_ + d;
        aOf[idx] = f2b(oacc[pq][dt][r]);
      }
}

// ---------------- output projection v2: kc=1, 64e x 64s tiles, BK=128, direct f32 out --------
// 256 blocks x 512 thr. Single writer per output element -> no split-K partials, no reduce
// kernel, no fences. Full-f32 accumulation over K=2048 (more accurate than bf16 partials).
__global__ __launch_bounds__(512, 2) void outproj_kernel(
    const u16* __restrict__ WoTf, const u16* __restrict__ aOf,
    float* __restrict__ out) {
  const int bid = blockIdx.x;          // 0..255
  const int bm = bid >> 6;             // 0..3   e-tile of 64
  const int bn = bid & 63;             // 0..63  s-tile of 64
  const int e0t = bm * 64, s0t = bn * 64;

  __shared__ u16 AhS[64 * 128], BhS[64 * 128];   // 16KB each, rows 256B swizzled
  char* AhB = (char*)AhS; char* BhB = (char*)BhS;

  const int tid = threadIdx.x;
  const int w = tid >> 6, lane = tid & 63;
  const int lr = lane & 15, lh = lane >> 4;
  const int wm = w >> 1, wn = w & 1;   // wave: e-strip wm*16, s-half wn*32

  f32x4 acc[2];
  acc[0] = (f32x4){0.f, 0.f, 0.f, 0.f};
  acc[1] = (f32x4){0.f, 0.f, 0.f, 0.f};

  for (int k0 = 0; k0 < 2048; k0 += 128) {
    __syncthreads();
#pragma unroll
    for (int j = 0; j < 2; ++j) {
      const int c = j * 512 + tid;               // 0..1023 chunks of 8 elems
      const int row = c >> 4, slot = c & 15;
      const int l = slot ^ (row & 7);            // inverse of the read-side XOR
      gl16(WoTf + (size_t)(e0t + row) * 2048 + k0 + l * 8, AhS + c * 8);
      gl16(aOf  + (size_t)(s0t + row) * 2048 + k0 + l * 8, BhS + c * 8);
    }
    __syncthreads();

#pragma unroll
    for (int ks = 0; ks < 4; ++ks) {
      const int m = wm * 16 + lr;
      const short8v afh = *reinterpret_cast<const short8v*>(
          AhB + m * 256 + ((ks * 64 + lh * 16) ^ ((m & 7) << 4)));
      short8v bfh[2];
#pragma unroll
      for (int nf = 0; nf < 2; ++nf) {
        const int n = wn * 32 + nf * 16 + lr;
        bfh[nf] = *reinterpret_cast<const short8v*>(
            BhB + n * 256 + ((ks * 64 + lh * 16) ^ ((n & 7) << 4)));
      }
      __builtin_amdgcn_s_setprio(1);
      acc[0] = mfma16(afh, bfh[0], acc[0]);
      acc[1] = mfma16(afh, bfh[1], acc[1]);
      __builtin_amdgcn_s_setprio(0);
    }
  }

  // ---- epilogue: direct f32 store (single writer per element) ----
  const int e0 = e0t + wm * 16 + lh * 4;
#pragma unroll
  for (int nf = 0; nf < 2; ++nf) {
    const int s = s0t + wn * 32 + nf * 16 + lr;
    float4 ov;
    ov.x = acc[nf][0]; ov.y = acc[nf][1]; ov.z = acc[nf][2]; ov.w = acc[nf][3];
    *reinterpret_cast<float4*>(out + (size_t)s * D_ + e0) = ov;
  }
}

extern "C" void kernel_launch(void* const* d_in, const int* in_sizes, int n_in,
                              void* d_out, int out_size, void* d_ws, size_t ws_size,
                              hipStream_t stream) {
  (void)in_sizes; (void)n_in; (void)out_size; (void)ws_size;
  const float* x   = (const float*)d_in[0];
  const float* Wq  = (const float*)d_in[3];
  const float* Wk  = (const float*)d_in[4];
  const float* Wv  = (const float*)d_in[5];
  const float* Wo  = (const float*)d_in[6];
  const float* lnw = (const float*)d_in[7];
  float* out = (float*)d_out;

  char* ws = (char*)d_ws;
  u16*  xf   = (u16*)(ws);                                     //  2 MB (fp16)
  u16*  WTf  = (u16*)(ws + ((size_t)2   << 20));               //  3 MB (fp16)
  u16*  WoTf = (u16*)(ws + ((size_t)5   << 20));               //  1 MB (bf16)
  float* k2  = (float*)(ws + ((size_t)6  << 20));              // 128 KB
  u16*  Qf   = (u16*)(ws + ((size_t)8   << 20));               // 16 MB (fp16)
  u16*  Kf   = (u16*)(ws + ((size_t)24  << 20));               // 16 MB (fp16)
  u16*  Vt   = (u16*)(ws + ((size_t)40  << 20));               // 16 MB (bf16)
  u16*  aOf  = (u16*)(ws + ((size_t)56  << 20));               // 16 MB (bf16)

  lnwt_kernel<<<dim3(1552), dim3(256), 0, stream>>>(x, lnw, Wq, Wk, Wv, Wo, xf, WTf, WoTf, k2);
  proj_kernel<<<dim3(64, 24), dim3(256), 0, stream>>>(xf, WTf, Qf, Kf, Vt, k2);
  attn_kernel<<<dim3(32, 16), dim3(256), 0, stream>>>(Qf, Kf, Vt, k2, aOf);
  outproj_kernel<<<dim3(256), dim3(512), 0, stream>>>(WoTf, aOf, out);
}

// Round 17
// 89.298 us; speedup vs baseline: 1.0305x; 1.0305x over previous
//
#include <hip/hip_runtime.h>
#include <cstdint>
#include <cstddef>

#define B_ 4
#define S_ 1024
#define D_ 256
#define H_ 8

typedef unsigned short u16;
typedef __attribute__((ext_vector_type(8))) short short8v;     // 8 x bf16 MFMA operand
typedef __attribute__((ext_vector_type(8))) _Float16 half8v;   // 8 x fp16 MFMA operand
typedef __attribute__((ext_vector_type(4))) float f32x4;       // MFMA accumulator
typedef __attribute__((ext_vector_type(4))) u16 u16x4;
typedef __attribute__((ext_vector_type(8))) u16 u16x8;

__device__ inline u16 f2b(float f) {            // fp32 -> bf16 RN-even
  unsigned u = __builtin_bit_cast(unsigned, f);
  unsigned r = (u + 0x7FFFu + ((u >> 16) & 1u)) >> 16;
  return (u16)r;
}
__device__ inline float b2f(u16 h) {
  return __builtin_bit_cast(float, ((unsigned)h) << 16);
}
__device__ inline u16 f2h(float f) {
  return __builtin_bit_cast(u16, (_Float16)f);
}
__device__ inline f32x4 mfma16(short8v a, short8v b, f32x4 c) {
  return __builtin_amdgcn_mfma_f32_16x16x32_bf16(a, b, c, 0, 0, 0);
}
__device__ inline f32x4 mfma16h(half8v a, half8v b, f32x4 c) {
  return __builtin_amdgcn_mfma_f32_16x16x32_f16(a, b, c, 0, 0, 0);
}
__device__ __forceinline__ void gl16(const u16* g, u16* l) {
  __builtin_amdgcn_global_load_lds((const uint32_t*)g, (uint32_t*)l, 16, 0, 0);
}

// ---- fused LayerNorm (0..1023) + W transpose (1024..1535) + k2 zero (1536..1551) ----
// k2 zeroing folded in (proj, the only k2 user, runs strictly after lnwt) -> the head-of-stream
// hipMemsetAsync dispatch is deleted.
__global__ __launch_bounds__(256) void lnwt_kernel(
    const float* __restrict__ x, const float* __restrict__ w,
    const float* __restrict__ Wq, const float* __restrict__ Wk,
    const float* __restrict__ Wv, const float* __restrict__ Wo,
    u16* __restrict__ xf, u16* __restrict__ WTf, u16* __restrict__ WoTf,
    float* __restrict__ k2) {
  const int bid = blockIdx.x;
  const int tid = threadIdx.x;
  if (bid < 1024) {
    // ---- LayerNorm: wave-per-row, 4 rows per block ----
    const int wid = tid >> 6, lane = tid & 63;
    const int row = bid * 4 + wid;                      // 0..4095
    const float4 v4 = *reinterpret_cast<const float4*>(x + (size_t)row * D_ + lane * 4);
    const float4 w4 = *reinterpret_cast<const float4*>(w + lane * 4);
    float s  = v4.x + v4.y + v4.z + v4.w;
    float s2 = v4.x * v4.x + v4.y * v4.y + v4.z * v4.z + v4.w * v4.w;
#pragma unroll
    for (int off = 1; off < 64; off <<= 1) {
      s  += __shfl_xor(s, off);
      s2 += __shfl_xor(s2, off);
    }
    const float mu  = s * (1.0f / D_);
    const float var = s2 * (1.0f / D_) - mu * mu;
    const float rr  = rsqrtf(var + 1e-5f);
    u16x4 o;
    o[0] = f2h((v4.x - mu) * rr * w4.x);
    o[1] = f2h((v4.y - mu) * rr * w4.y);
    o[2] = f2h((v4.z - mu) * rr * w4.z);
    o[3] = f2h((v4.w - mu) * rr * w4.w);
    *reinterpret_cast<u16x4*>(xf + (size_t)row * D_ + lane * 4) = o;
  } else if (bid >= 1536) {
    // ---- zero k2: 16 blocks x 256 thr x 32B = 128KB ----
    const size_t i = ((size_t)(bid - 1536) * 256 + tid) * 8;
    const float4 z4 = {0.f, 0.f, 0.f, 0.f};
    *reinterpret_cast<float4*>(k2 + i)     = z4;
    *reinterpret_cast<float4*>(k2 + i + 4) = z4;
  } else {
    // ---- weight transpose: 4 tiles per block ----
    __shared__ float t[32][33];
    const int tc = tid & 31, tr = tid >> 5;
    const int zb = (bid - 1024) * 4;
#pragma unroll
    for (int i = 0; i < 4; ++i) {
      const int z = zb + i;                             // 0..2047
      if (i) __syncthreads();                           // prior tile's reads done
      if (z < 1536) {
        const int wm = z >> 6;                          // 0..23
        const int mat = wm >> 3, h = wm & 7;
        const float* src = (mat == 0 ? Wq : mat == 1 ? Wk : Wv) + (size_t)h * 65536;
        const int t6 = z & 63;
        const int r0 = (t6 >> 3) * 32, c0 = (t6 & 7) * 32;
#pragma unroll
        for (int k = 0; k < 4; ++k)
          t[tr + k * 8][tc] = src[(size_t)(r0 + tr + k * 8) * 256 + c0 + tc];
        __syncthreads();
        u16* df = WTf + (size_t)wm * 65536;
#pragma unroll
        for (int k = 0; k < 4; ++k) {
          const float v = t[tc][tr + k * 8];
          df[(size_t)(c0 + tr + k * 8) * 256 + r0 + tc] = f2h(v);
        }
      } else {
        const int z2 = z - 1536;                        // 0..511
        const int r0 = (z2 >> 3) * 32, c0 = (z2 & 7) * 32;
#pragma unroll
        for (int k = 0; k < 4; ++k)
          t[tr + k * 8][tc] = Wo[(size_t)(r0 + tr + k * 8) * 256 + c0 + tc];
        __syncthreads();
#pragma unroll
        for (int k = 0; k < 4; ++k) {
          const float v = t[tc][tr + k * 8];
          WoTf[(size_t)(c0 + tr + k * 8) * 2048 + r0 + tc] = f2b(v);
        }
      }
    }
  }
}

// ---------------- Q/K/V projection: single-term fp16, BK=64; K-epilogue emits k2 ----------------
__global__ __launch_bounds__(256, 3) void proj_kernel(
    const u16* __restrict__ xf, const u16* __restrict__ WTf,
    u16* __restrict__ Qf, u16* __restrict__ Kf,
    u16* __restrict__ Vt, float* __restrict__ k2g) {
  const int z = blockIdx.y;            // 0..23
  const int mat = z >> 3, h = z & 7;
  const int xb = blockIdx.x;           // 0..63

  const u16 *Ap, *Bp;
  int arow0, brow0;
  if (mat < 2) {            // A = WT (M = e), B = x (N = s)
    Ap = WTf + (size_t)z * 65536; arow0 = (xb >> 5) * 128;
    Bp = xf;                      brow0 = (xb & 31) * 128;
  } else {                  // A = x (M = s), B = WT (N = d)
    Ap = xf;                      arow0 = (xb & 31) * 128;
    Bp = WTf + (size_t)z * 65536; brow0 = (xb >> 5) * 128;
  }

  __shared__ u16 LS[2 * 128 * 64];     // 32KB: A tile | B tile (reused by epilogue)
  u16* AS = LS; u16* BS = LS + 128 * 64;
  char* LSb = (char*)LS;
  char* ASb = (char*)AS; char* BSb = (char*)BS;

  const int tid = threadIdx.x;
  const int w = tid >> 6, lane = tid & 63;
  const int lr = lane & 15, lh = lane >> 4;
  const int wm = w >> 1, wn = w & 1;

  f32x4 acc[4][4];
#pragma unroll
  for (int i = 0; i < 4; ++i)
#pragma unroll
    for (int j = 0; j < 4; ++j) acc[i][j] = (f32x4){0.f, 0.f, 0.f, 0.f};

  for (int k0 = 0; k0 < 256; k0 += 64) {
    __syncthreads();
#pragma unroll
    for (int j = 0; j < 4; ++j) {
      const int c0 = j * 256 + w * 64;
      const int c = c0 + lane;
      const int m = c >> 3, sl = c & 7;
      const int l = sl ^ (m & 7);
      gl16(Ap + (size_t)(arow0 + m) * 256 + k0 + l * 8, AS + c0 * 8);
    }
#pragma unroll
    for (int j = 0; j < 4; ++j) {
      const int c0 = j * 256 + w * 64;
      const int c = c0 + lane;
      const int n = c >> 3, sl = c & 7;
      const int l = sl ^ (n & 7);
      gl16(Bp + (size_t)(brow0 + n) * 256 + k0 + l * 8, BS + c0 * 8);
    }
    __syncthreads();

#pragma unroll
    for (int ks = 0; ks < 2; ++ks) {
      half8v af[4], bf[4];
#pragma unroll
      for (int mf = 0; mf < 4; ++mf) {
        const int m = wm * 64 + mf * 16 + lr;
        af[mf] = *reinterpret_cast<const half8v*>(
            ASb + m * 128 + (((ks * 4 + lh) * 16) ^ ((m & 7) << 4)));
      }
#pragma unroll
      for (int nf = 0; nf < 4; ++nf) {
        const int n = wn * 64 + nf * 16 + lr;
        bf[nf] = *reinterpret_cast<const half8v*>(
            BSb + n * 128 + (((ks * 4 + lh) * 16) ^ ((n & 7) << 4)));
      }
      __builtin_amdgcn_s_setprio(1);
#pragma unroll
      for (int mf = 0; mf < 4; ++mf)
#pragma unroll
        for (int nf = 0; nf < 4; ++nf)
          acc[mf][nf] = mfma16h(af[mf], bf[nf], acc[mf][nf]);
      __builtin_amdgcn_s_setprio(0);
    }
  }

  __syncthreads();

  if (mat < 2) {
    u16* Hf = (mat == 0) ? Qf : Kf;
#pragma unroll
    for (int mf = 0; mf < 4; ++mf)
#pragma unroll
      for (int nf = 0; nf < 4; ++nf) {
        const int sl_ = wn * 64 + nf * 16 + lr;
        const int el_ = wm * 64 + mf * 16 + lh * 4;
        u16x4 hv;
#pragma unroll
        for (int r = 0; r < 4; ++r) hv[r] = f2h(acc[mf][nf][r]);
        *reinterpret_cast<u16x4*>(LSb + sl_ * 256 + ((el_ * 2) ^ ((sl_ & 7) << 4))) = hv;
      }
    // ---- k2 partials (K only): per s-row, sum of rounded-fp16 squares ----
    if (mat == 1) {
#pragma unroll
      for (int nf = 0; nf < 4; ++nf) {
        float p = 0.f;
#pragma unroll
        for (int mf = 0; mf < 4; ++mf)
#pragma unroll
          for (int r = 0; r < 4; ++r) {
            const float v = (float)(_Float16)acc[mf][nf][r];
            p = fmaf(v, v, p);
          }
        p += __shfl_xor(p, 16);
        p += __shfl_xor(p, 32);
        if (lh == 0) {
          const int s = brow0 + wn * 64 + nf * 16 + lr;
          const int bb = s >> 10;
          atomicAdd(&k2g[(size_t)(bb * H_ + h) * S_ + (s & 1023)], p);
        }
      }
    }
    __syncthreads();
#pragma unroll
    for (int i = 0; i < 8; ++i) {
      const int c = i * 256 + tid;
      const int sl_ = c >> 4, ch = c & 15;
      const u16x8 v = *reinterpret_cast<const u16x8*>(
          LSb + sl_ * 256 + ((ch * 16) ^ ((sl_ & 7) << 4)));
      const int s = brow0 + sl_;
      const int bb = s >> 10;
      *reinterpret_cast<u16x8*>(
          Hf + ((size_t)(bb * H_ + h) * S_ + (s & 1023)) * D_ + arow0 + ch * 8) = v;
    }
  } else {
#pragma unroll
    for (int mf = 0; mf < 4; ++mf)
#pragma unroll
      for (int nf = 0; nf < 4; ++nf) {
        const int dl_ = wn * 64 + nf * 16 + lr;
        const int sl_ = wm * 64 + mf * 16 + lh * 4;
        u16x4 hv;
#pragma unroll
        for (int r = 0; r < 4; ++r) hv[r] = f2b(acc[mf][nf][r]);
        *reinterpret_cast<u16x4*>(LSb + dl_ * 256 + ((sl_ * 2) ^ ((dl_ & 7) << 4))) = hv;
      }
    __syncthreads();
#pragma unroll
    for (int i = 0; i < 8; ++i) {
      const int c = i * 256 + tid;
      const int dl_ = c >> 4, ch = c & 15;
      const u16x8 v = *reinterpret_cast<const u16x8*>(
          LSb + dl_ * 256 + ((ch * 16) ^ ((dl_ & 7) << 4)));
      const int d = brow0 + dl_;
      const int sg = arow0 + ch * 8;
      const int bb = sg >> 10;
      *reinterpret_cast<u16x8*>(
          Vt + ((size_t)(bb * H_ + h) * D_ + d) * S_ + (sg & 1023)) = v;
    }
  }
}

// ---------------- fused RBF attention v17: 2-barrier counted-vmcnt pipeline + tail peel ------
__global__ __launch_bounds__(256, 2) void attn_kernel(
    const u16* __restrict__ Qf, const u16* __restrict__ Kf,
    const u16* __restrict__ Vt, const float* __restrict__ k2,
    u16* __restrict__ aOf) {
  const int bh  = blockIdx.x;   // 0..31 (fast -> XCD locality)
  const int qt  = blockIdx.y;   // 0..15
  const int tid = threadIdx.x;
  const int w = tid >> 6, lane = tid & 63;
  const int lr = lane & 15, lh = lane >> 4;
  const int qg = w >> 1, kvh = w & 1;

  __shared__ u16 KS[64 * 256];    // fp16, rows 512B swizzled     (32KB)
  __shared__ u16 VS[256 * 64];    // bf16, rows 128B swizzled     (32KB)
  __shared__ u16 PS[64 * 64];     // bf16, rows 128B swizzled     (8KB)
  __shared__ float K2S[1024];     // k2 row for this bh           (4KB)
  char* KB = (char*)KS; char* VB = (char*)VS; char* PB = (char*)PS;

  half8v qf[2][8];
#pragma unroll
  for (int at = 0; at < 2; ++at) {
    const int qrow = qt * 64 + qg * 32 + at * 16 + lr;
    const size_t qbase = ((size_t)(bh * S_) + qrow) * D_ + lh * 8;
#pragma unroll
    for (int ds = 0; ds < 8; ++ds)
      qf[at][ds] = *reinterpret_cast<const half8v*>(Qf + qbase + ds * 32);
  }

  const size_t kgbase = (size_t)(bh * S_);
  const size_t vgbase = (size_t)(bh * D_);

  // ---- prologue: issue K[0] (8), k2 (1), V[0] (8); q2 computes under the flight ----
#pragma unroll
  for (int j = 0; j < 8; ++j) {
    const int c0 = j * 256 + w * 64;
    const int c = c0 + lane;
    const int row = c >> 5, slot = c & 31;
    gl16(Kf + (kgbase + row) * D_ + ((slot ^ (row & 7)) << 3), KS + c0 * 8);
  }
  gl16((const u16*)(k2 + (size_t)bh * S_) + tid * 8, (u16*)K2S + tid * 8);
#pragma unroll
  for (int j = 0; j < 8; ++j) {
    const int c0 = j * 256 + w * 64;
    const int c = c0 + lane;
    const int d = c >> 3, slot = c & 7;
    gl16(Vt + (vgbase + d) * S_ + ((slot ^ (d & 7)) << 3), VS + c0 * 8);
  }

  // ---- q2 fully in-register: after xor16+xor32 every lane holds q2(row=lr) ----
  float q2v[2];
#pragma unroll
  for (int at = 0; at < 2; ++at) {
    float p = 0.f;
#pragma unroll
    for (int ds = 0; ds < 8; ++ds)
#pragma unroll
      for (int j = 0; j < 8; ++j) {
        const float v = (float)qf[at][ds][j];
        p = fmaf(v, v, p);
      }
    p += __shfl_xor(p, 16);
    p += __shfl_xor(p, 32);
    q2v[at] = p;
  }

  asm volatile("s_waitcnt vmcnt(8)" ::: "memory");   // K[0]+k2 landed; V[0] in flight
  __builtin_amdgcn_sched_barrier(0);
  __builtin_amdgcn_s_barrier();

  f32x4 oacc[4][4];
#pragma unroll
  for (int i = 0; i < 4; ++i)
#pragma unroll
    for (int j = 0; j < 4; ++j) oacc[i][j] = (f32x4){0.f, 0.f, 0.f, 0.f};

  for (int kt = 0; kt < 16; ++kt) {
    const int last = (kt == 15);

    // per-wave counted wait: K[kt] landed (8 newest outstanding = V[kt], still flying)
    asm volatile("s_waitcnt vmcnt(8)" ::: "memory");
    __builtin_amdgcn_sched_barrier(0);

    // k2 slice for this tile from LDS (broadcast reads, conflict-free)
    f32x4 k2v[2];
#pragma unroll
    for (int bt = 0; bt < 2; ++bt)
      k2v[bt] = *reinterpret_cast<const f32x4*>(
          K2S + kt * 64 + kvh * 32 + bt * 16 + lh * 4);

    // ---- QK^T swapped: pacc = mfma(K, Q) -> lane holds P^T: rows kv=lh*4+r, col q=lr ----
    f32x4 pacc[2][2];
#pragma unroll
    for (int at = 0; at < 2; ++at)
#pragma unroll
      for (int bt = 0; bt < 2; ++bt) pacc[at][bt] = (f32x4){0.f, 0.f, 0.f, 0.f};
#pragma unroll
    for (int ds = 0; ds < 8; ++ds) {
      half8v kf[2];
#pragma unroll
      for (int bt = 0; bt < 2; ++bt) {
        const int krow = kvh * 32 + bt * 16 + lr;
        kf[bt] = *reinterpret_cast<const half8v*>(
            KB + krow * 512 + (((ds * 64) + lh * 16) ^ ((krow & 7) << 4)));
      }
      __builtin_amdgcn_s_setprio(1);
#pragma unroll
      for (int at = 0; at < 2; ++at)
#pragma unroll
        for (int bt = 0; bt < 2; ++bt)
          pacc[at][bt] = mfma16h(kf[bt], qf[at][ds], pacc[at][bt]);
      __builtin_amdgcn_s_setprio(0);
    }

    // ---- exp + P^T write: u16x4 along kv per (at,bt) -> 4 x ds_write_b64 ----
#pragma unroll
    for (int at = 0; at < 2; ++at) {
      const int q = qg * 32 + at * 16 + lr;
#pragma unroll
      for (int bt = 0; bt < 2; ++bt) {
        const int kv0 = kvh * 32 + bt * 16 + lh * 4;
        u16x4 pv;
#pragma unroll
        for (int r = 0; r < 4; ++r) {
          float d2 = q2v[at] + k2v[bt][r] - 2.0f * pacc[at][bt][r];
          d2 = fmaxf(d2, 0.f);
          pv[r] = f2b(__expf(-d2));
        }
        *reinterpret_cast<u16x4*>(PB + q * 128 + ((kv0 * 2) ^ ((q & 7) << 4))) = pv;
      }
    }
    asm volatile("s_waitcnt vmcnt(0) lgkmcnt(0)" ::: "memory");  // V[kt] landed; KS reads + P done
    __builtin_amdgcn_sched_barrier(0);
    __builtin_amdgcn_s_barrier();          // BAR A

    // ---- issue K[kt+1] staging (skipped on last iter): waited per-wave at next loop top ----
    if (!last) {
#pragma unroll
      for (int j = 0; j < 8; ++j) {
        const int c0 = j * 256 + w * 64;
        const int c = c0 + lane;
        const int row = c >> 5, slot = c & 31;
        gl16(Kf + (kgbase + (kt + 1) * 64 + row) * D_ + ((slot ^ (row & 7)) << 3),
             KS + c0 * 8);
      }
    }

    // ---- PV: wave owns d in [w*64, w*64+64) for all 64 q ----
    short8v vfr[4][2];
#pragma unroll
    for (int dt = 0; dt < 4; ++dt)
#pragma unroll
      for (int ks = 0; ks < 2; ++ks) {
        const int d = w * 64 + dt * 16 + lr;
        vfr[dt][ks] = *reinterpret_cast<const short8v*>(
            VB + d * 128 + (((ks * 64) + lh * 16) ^ ((d & 7) << 4)));
      }
#pragma unroll
    for (int pq = 0; pq < 4; ++pq) {
      short8v pa[2];
#pragma unroll
      for (int ks = 0; ks < 2; ++ks) {
        const int q = pq * 16 + lr;
        pa[ks] = *reinterpret_cast<const short8v*>(
            PB + q * 128 + (((ks * 64) + lh * 16) ^ ((q & 7) << 4)));
      }
      __builtin_amdgcn_s_setprio(1);
#pragma unroll
      for (int dt = 0; dt < 4; ++dt) {
        oacc[pq][dt] = mfma16(pa[0], vfr[dt][0], oacc[pq][dt]);
        oacc[pq][dt] = mfma16(pa[1], vfr[dt][1], oacc[pq][dt]);
      }
      __builtin_amdgcn_s_setprio(0);
    }
    if (!last) {
      asm volatile("s_waitcnt lgkmcnt(0)" ::: "memory");   // VS/PS reads done (no vmem wait)
      __builtin_amdgcn_sched_barrier(0);
      __builtin_amdgcn_s_barrier();        // BAR B

      // ---- issue V[kt+1] staging: flies under next QK, drained at next BAR A ----
#pragma unroll
      for (int j = 0; j < 8; ++j) {
        const int c0 = j * 256 + w * 64;
        const int c = c0 + lane;
        const int d = c >> 3, slot = c & 7;
        gl16(Vt + (vgbase + d) * S_ + (kt + 1) * 64 + ((slot ^ (d & 7)) << 3),
             VS + c0 * 8);
      }
    }
  }

  const int bb = bh >> 3, hh = bh & 7;
#pragma unroll
  for (int pq = 0; pq < 4; ++pq)
#pragma unroll
    for (int dt = 0; dt < 4; ++dt)
#pragma unroll
      for (int r = 0; r < 4; ++r) {
        const int s = qt * 64 + pq * 16 + lh * 4 + r;
        const int d = w * 64 + dt * 16 + lr;
        const size_t idx = ((size_t)(bb * S_) + s) * (H_ * D_) + hh * D_ + d;
        aOf[idx] = f2b(oacc[pq][dt][r]);
      }
}

// ---------------- output projection, split-K=4, bf16 partials ----------------
__global__ __launch_bounds__(512, 4) void outproj_kernel(
    const u16* __restrict__ WoTf, const u16* __restrict__ aOf,
    u16* __restrict__ pbuf) {
  const int xb = blockIdx.x;          // 0..63
  const int kc = blockIdx.y;          // 0..3
  const int bm = xb >> 5, bn = xb & 31;
  const int arow0 = bm * 128, brow0 = bn * 128;

  __shared__ u16 AhS[128 * 64], BhS[128 * 64];
  char* AhB = (char*)AhS; char* BhB = (char*)BhS;

  const int tid = threadIdx.x;
  const int w = tid >> 6, lane = tid & 63;
  const int lr = lane & 15, lh = lane >> 4;
  const int wr = w >> 2, wc = w & 3;

  f32x4 acc[4][2];
#pragma unroll
  for (int i = 0; i < 4; ++i)
#pragma unroll
    for (int j = 0; j < 2; ++j) acc[i][j] = (f32x4){0.f, 0.f, 0.f, 0.f};

  for (int k0 = kc * 512; k0 < kc * 512 + 512; k0 += 64) {
#pragma unroll
    for (int i = 0; i < 2; ++i) {
      const int c = tid + i * 512;
      const int row = c >> 3, slot = c & 7;
      const int off = row * 128 + ((slot * 16) ^ ((row & 7) << 4));
      const size_t ga = (size_t)(arow0 + row) * 2048 + k0 + slot * 8;
      const size_t gb = (size_t)(brow0 + row) * 2048 + k0 + slot * 8;
      *reinterpret_cast<short8v*>(AhB + off) = *reinterpret_cast<const short8v*>(WoTf + ga);
      *reinterpret_cast<short8v*>(BhB + off) = *reinterpret_cast<const short8v*>(aOf + gb);
    }
    __syncthreads();
#pragma unroll
    for (int ks = 0; ks < 2; ++ks) {
      short8v afh[4], bfh[2];
#pragma unroll
      for (int mf = 0; mf < 4; ++mf) {
        const int m = wr * 64 + mf * 16 + lr;
        afh[mf] = *reinterpret_cast<const short8v*>(
            AhB + m * 128 + (((ks * 64) + lh * 16) ^ ((m & 7) << 4)));
      }
#pragma unroll
      for (int nf = 0; nf < 2; ++nf) {
        const int n = wc * 32 + nf * 16 + lr;
        bfh[nf] = *reinterpret_cast<const short8v*>(
            BhB + n * 128 + (((ks * 64) + lh * 16) ^ ((n & 7) << 4)));
      }
      __builtin_amdgcn_s_setprio(1);
#pragma unroll
      for (int mf = 0; mf < 4; ++mf)
#pragma unroll
        for (int nf = 0; nf < 2; ++nf)
          acc[mf][nf] = mfma16(afh[mf], bfh[nf], acc[mf][nf]);
      __builtin_amdgcn_s_setprio(0);
    }
    __syncthreads();
  }

  u16* pout = pbuf + (size_t)kc * (4096 * 256);
#pragma unroll
  for (int mf = 0; mf < 4; ++mf) {
    const int e0 = bm * 128 + wr * 64 + mf * 16 + lh * 4;
#pragma unroll
    for (int nf = 0; nf < 2; ++nf) {
      const int s = bn * 128 + wc * 32 + nf * 16 + lr;
      u16x4 hv;
#pragma unroll
      for (int r = 0; r < 4; ++r) hv[r] = f2b(acc[mf][nf][r]);
      *reinterpret_cast<u16x4*>(pout + (size_t)s * D_ + e0) = hv;
    }
  }
}

// ---------------- split-K reduce: out = sum of 4 bf16 partials ----------------
__global__ __launch_bounds__(256) void reduce_kernel(const u16* __restrict__ pbuf,
                                                     float* __restrict__ out) {
  const size_t i = ((size_t)blockIdx.x * 256 + threadIdx.x) * 8;
  const size_t C = (size_t)4096 * 256;
  const u16x8 a = *reinterpret_cast<const u16x8*>(pbuf + i);
  const u16x8 b = *reinterpret_cast<const u16x8*>(pbuf + C + i);
  const u16x8 c = *reinterpret_cast<const u16x8*>(pbuf + 2 * C + i);
  const u16x8 d = *reinterpret_cast<const u16x8*>(pbuf + 3 * C + i);
  float4 o0, o1;
#pragma unroll
  for (int j = 0; j < 8; ++j) {
    const float v = b2f((u16)a[j]) + b2f((u16)b[j]) + b2f((u16)c[j]) + b2f((u16)d[j]);
    if (j < 4) (&o0.x)[j] = v; else (&o1.x)[j - 4] = v;
  }
  *reinterpret_cast<float4*>(out + i)     = o0;
  *reinterpret_cast<float4*>(out + i + 4) = o1;
}

extern "C" void kernel_launch(void* const* d_in, const int* in_sizes, int n_in,
                              void* d_out, int out_size, void* d_ws, size_t ws_size,
                              hipStream_t stream) {
  (void)in_sizes; (void)n_in; (void)out_size; (void)ws_size;
  const float* x   = (const float*)d_in[0];
  const float* Wq  = (const float*)d_in[3];
  const float* Wk  = (const float*)d_in[4];
  const float* Wv  = (const float*)d_in[5];
  const float* Wo  = (const float*)d_in[6];
  const float* lnw = (const float*)d_in[7];
  float* out = (float*)d_out;

  char* ws = (char*)d_ws;
  u16*  xf   = (u16*)(ws);                                     //  2 MB (fp16)
  u16*  WTf  = (u16*)(ws + ((size_t)2   << 20));               //  3 MB (fp16)
  u16*  WoTf = (u16*)(ws + ((size_t)5   << 20));               //  1 MB (bf16)
  float* k2  = (float*)(ws + ((size_t)6  << 20));              // 128 KB
  u16*  Qf   = (u16*)(ws + ((size_t)8   << 20));               // 16 MB (fp16)
  u16*  Kf   = (u16*)(ws + ((size_t)24  << 20));               // 16 MB (fp16)
  u16*  Vt   = (u16*)(ws + ((size_t)40  << 20));               // 16 MB (bf16)
  u16*  aOf  = (u16*)(ws + ((size_t)56  << 20));               // 16 MB (bf16)
  u16*  pbuf = (u16*)(ws + ((size_t)72  << 20));               //  8 MB (4 x 2MB bf16)

  lnwt_kernel<<<dim3(1552), dim3(256), 0, stream>>>(x, lnw, Wq, Wk, Wv, Wo, xf, WTf, WoTf, k2);
  proj_kernel<<<dim3(64, 24), dim3(256), 0, stream>>>(xf, WTf, Qf, Kf, Vt, k2);
  attn_kernel<<<dim3(32, 16), dim3(256), 0, stream>>>(Qf, Kf, Vt, k2, aOf);
  outproj_kernel<<<dim3(64, 4), dim3(512), 0, stream>>>(WoTf, aOf, pbuf);
  reduce_kernel<<<dim3(512), dim3(256), 0, stream>>>(pbuf, out);
}